// Round 12
// baseline (337.226 us; speedup 1.0000x reference)
//
#include <hip/hip_runtime.h>
#include <stdint.h>

// B=2, S=2048, DM=1024, H=16, HD=64
// out_size = 4194304 (out f32) + 134217728 (attn f32)

typedef _Float16 f16x8 __attribute__((ext_vector_type(8)));
typedef __fp16 fp16v2 __attribute__((ext_vector_type(2)));
typedef float f32x4 __attribute__((ext_vector_type(4)));
typedef unsigned long long ull;

static_assert(sizeof(f16x8) == 16, "f16x8 must be 16B");

#define MFMA16(a, b, c) __builtin_amdgcn_mfma_f32_16x16x32_f16((a), (b), (c), 0, 0, 0)

__device__ __forceinline__ unsigned short f2h_(float f) {
  _Float16 h = (_Float16)f;
  return __builtin_bit_cast(unsigned short, h);
}

// pack two f32 -> two f16 in one v_cvt_pkrtz_f16_f32
__device__ __forceinline__ unsigned pk2_(float a, float b) {
  fp16v2 h = __builtin_amdgcn_cvt_pkrtz(a, b);
  return __builtin_bit_cast(unsigned, h);
}

// ---------------------------------------------------------------------------
// 1) fused prep: blocks 0..8191 convert fp32->fp16 (q,k,v,W*); blocks
//    8192..8703 pack mask int32 -> bitmask u64 [B*S][32].
//    All source reads nontemporal (read-once streams; keep L2 for xb).
// ---------------------------------------------------------------------------
__global__ __launch_bounds__(256) void prep_kernel(
    const float* __restrict__ q, const float* __restrict__ k,
    const float* __restrict__ v, const float* __restrict__ wq,
    const float* __restrict__ wk, const float* __restrict__ wv,
    const float* __restrict__ wf, unsigned short* __restrict__ dst,
    const int* __restrict__ mask, ull* __restrict__ mb) {
  int bid = blockIdx.x;
  if (bid < 8192) {
    long e0 = ((long)bid * 256 + threadIdx.x) * 8;
    const float* src; long off;
    if (e0 < 4194304L)       { src = q;  off = e0; }
    else if (e0 < 8388608L)  { src = k;  off = e0 - 4194304L; }
    else if (e0 < 12582912L) { src = v;  off = e0 - 8388608L; }
    else if (e0 < 13631488L) { src = wq; off = e0 - 12582912L; }
    else if (e0 < 14680064L) { src = wk; off = e0 - 13631488L; }
    else if (e0 < 15728640L) { src = wv; off = e0 - 14680064L; }
    else                     { src = wf; off = e0 - 15728640L; }
    f32x4 a = __builtin_nontemporal_load((const f32x4*)(src + off));
    f32x4 b = __builtin_nontemporal_load((const f32x4*)(src + off + 4));
    uint4 o;
    o.x = pk2_(a[0], a[1]);
    o.y = pk2_(a[2], a[3]);
    o.z = pk2_(b[0], b[1]);
    o.w = pk2_(b[2], b[3]);
    *(uint4*)(dst + e0) = o;
  } else {
    int wid = (int)(((bid - 8192) * 256 + threadIdx.x) >> 6);
    int lane = threadIdx.x & 63;
    for (int w = wid; w < 131072; w += 2048) {
      int val = __builtin_nontemporal_load(mask + (long)w * 64 + lane);
      ull bits = __ballot(val != 0);
      if (lane == 0) mb[w] = bits;
    }
  }
}

// ---------------------------------------------------------------------------
// 3) GEMM: C[i][j] = sum_k A[i][k]*B[j][k] + bias[i]; 128x128 tile, 4 waves,
//    BK=64, reg-staged swizzled LDS, 4x4 acc per wave. Ping-pong double-
//    buffer: stage kt+1 before compute kt, ONE barrier/kt.
// ---------------------------------------------------------------------------
__device__ __forceinline__ void gemm_body(
    const unsigned short* __restrict__ A, const unsigned short* __restrict__ Bm,
    const float* __restrict__ bias, unsigned short* __restrict__ outb,
    float* __restrict__ outf, int mode) {
  __shared__ unsigned short Al[2][128 * 64];
  __shared__ unsigned short Bl[2][128 * 64];
  const int tid = threadIdx.x, lane = tid & 63, wave = tid >> 6;
  const int lo = lane & 15, hi = lane >> 4;
  const int wi = wave >> 1, wj = wave & 1;
  const int ib = blockIdx.y << 7, jb = blockIdx.x << 7;
  const int cb0 = hi << 4;
  f32x4 acc[4][4] = {};

#define GSTAGE(KT, BUF)                                                         \
  _Pragma("unroll") for (int i = 0; i < 4; ++i) {                               \
    int u = tid + (i << 8), r = u >> 3, c = u & 7;                              \
    uint4 av = *(const uint4*)(A + (long)(ib + r) * 1024 + ((KT) << 6) + c * 8);\
    uint4 bv = *(const uint4*)(Bm + (long)(jb + r) * 1024 + ((KT) << 6) + c * 8);\
    *(uint4*)((char*)Al[BUF] + r * 128 + ((c * 16) ^ ((r & 7) << 4))) = av;     \
    *(uint4*)((char*)Bl[BUF] + r * 128 + ((c * 16) ^ ((r & 7) << 4))) = bv;     \
  }

  GSTAGE(0, 0);
  __syncthreads();
  for (int kt = 0; kt < 16; ++kt) {
    const int cur = kt & 1;
    if (kt < 15) GSTAGE(kt + 1, cur ^ 1);
    f16x8 af[4][2], bfr[4][2];
#pragma unroll
    for (int it = 0; it < 4; ++it) {
      int r = (wi << 6) + (it << 4) + lo;
      af[it][0] = *(const f16x8*)((char*)Al[cur] + r * 128 + (cb0 ^ ((r & 7) << 4)));
      af[it][1] = *(const f16x8*)((char*)Al[cur] + r * 128 + ((64 + cb0) ^ ((r & 7) << 4)));
    }
#pragma unroll
    for (int jt = 0; jt < 4; ++jt) {
      int r = (wj << 6) + (jt << 4) + lo;
      bfr[jt][0] = *(const f16x8*)((char*)Bl[cur] + r * 128 + (cb0 ^ ((r & 7) << 4)));
      bfr[jt][1] = *(const f16x8*)((char*)Bl[cur] + r * 128 + ((64 + cb0) ^ ((r & 7) << 4)));
    }
#pragma unroll
    for (int it = 0; it < 4; ++it)
#pragma unroll
      for (int jt = 0; jt < 4; ++jt) {
        acc[it][jt] = MFMA16(af[it][0], bfr[jt][0], acc[it][jt]);
        acc[it][jt] = MFMA16(af[it][1], bfr[jt][1], acc[it][jt]);
      }
    __syncthreads();
  }
#pragma unroll
  for (int it = 0; it < 4; ++it)
#pragma unroll
    for (int jt = 0; jt < 4; ++jt) {
      f32x4 vv = acc[it][jt];
      int i0 = ib + (wi << 6) + (it << 4) + (hi << 2);
      int j = jb + (wj << 6) + (jt << 4) + lo;
      float4 bb = *(const float4*)(bias + i0);
      vv[0] += bb.x; vv[1] += bb.y; vv[2] += bb.z; vv[3] += bb.w;
      if (mode == 2) {
        float4 st; st.x = vv[0]; st.y = vv[1]; st.z = vv[2]; st.w = vv[3];
        *(float4*)(outf + (long)j * 1024 + i0) = st;
      } else {
        int h = i0 >> 6, dd = i0 & 63, b2 = j >> 11, s2 = j & 2047;
        if (mode == 0) {
          ull pk = (ull)f2h_(vv[0]) | ((ull)f2h_(vv[1]) << 16) |
                   ((ull)f2h_(vv[2]) << 32) | ((ull)f2h_(vv[3]) << 48);
          *(ull*)(outb + ((long)((b2 * 16 + h) * 2048 + s2)) * 64 + dd) = pk;
        } else {
          unsigned short* p = outb + ((long)((b2 * 16 + h) * 64 + dd)) * 2048 + s2;
          p[0] = f2h_(vv[0]); p[2048] = f2h_(vv[1]);
          p[4096] = f2h_(vv[2]); p[6144] = f2h_(vv[3]);
        }
      }
    }
}

__global__ __launch_bounds__(256) void gemm_qkv(
    const unsigned short* __restrict__ xb, const float* __restrict__ bq,
    const float* __restrict__ bk, const float* __restrict__ bv,
    unsigned short* __restrict__ outbase) {
  const int z = blockIdx.z;
  const unsigned short* A = xb + 12582912 + (long)z * 1048576;
  const unsigned short* Bm = xb + (long)z * 4194304;
  const float* bias = (z == 0) ? bq : ((z == 1) ? bk : bv);
  unsigned short* outp = outbase + (long)z * 4194304;
  gemm_body(A, Bm, bias, outp, nullptr, (z == 2) ? 1 : 0);
}

__global__ __launch_bounds__(256) void gemm_f(
    const unsigned short* __restrict__ xb, const unsigned short* __restrict__ oh,
    const float* __restrict__ bias, float* __restrict__ outf) {
  gemm_body(xb + 15728640, oh, bias, nullptr, outf, 2);
}

// ---------------------------------------------------------------------------
// 4) attention monolith, ping-pong double-buffer (R10 champion) + T5 setprio
//    around MFMA clusters (isolated — no asm, no sched_barrier).
// ---------------------------------------------------------------------------
__global__ __launch_bounds__(256, 2) void attn_kernel(
    const unsigned short* __restrict__ qh, const unsigned short* __restrict__ kh,
    const unsigned short* __restrict__ vt, const ull* __restrict__ mb,
    float* __restrict__ attnp, unsigned short* __restrict__ oh) {
  __shared__ unsigned short Ks[2][128 * 64];   // [k][d] swizzled, db (32 KB)
  __shared__ unsigned short Vs[2][64 * 128];   // [d][s] swizzled, db (32 KB)
  __shared__ unsigned short Ps[64 * 128];      // [q][k] swizzled, per-wave rows
  const int tid = threadIdx.x, lane = tid & 63, wave = tid >> 6;
  const int lo = lane & 15, hi = lane >> 4;
  const int cb0 = hi << 4;
  int id = blockIdx.x;
  int wgid = (id & 7) * 128 + (id >> 3);   // bijective XCD swizzle (nwg=1024)
  const int bh = wgid >> 5, b_ = bh >> 4;
  const int q0 = (wgid & 31) << 6;
  const float cs = 0.18033688011112042f;   // (1/8) * log2(e)

  const int rq = (wave << 4) + lo;   // local q row (0..63)
  const int qg = q0 + rq;            // global q
  const int swq = (rq & 7) << 4;
  const unsigned short* qp = qh + ((long)bh * 2048 + qg) * 64;
  f16x8 aq0 = *(const f16x8*)(qp + (hi << 3));
  f16x8 aq1 = *(const f16x8*)(qp + 32 + (hi << 3));
  const ull* mrow = mb + (long)(b_ * 2048 + qg) * 32;
  const unsigned short* khb = kh + (long)bh * 2048 * 64;
  const unsigned short* vtb = vt + (long)bh * 64 * 2048;

  float ll = 0.f;
  f32x4 oacc[4] = {};

#define STAGE_KV(KT, BUF)                                                      \
  _Pragma("unroll") for (int i = 0; i < 4; ++i) {                              \
    int u = tid + (i << 8);                                                    \
    { int r = u >> 3, c = u & 7;                                               \
      uint4 d = *(const uint4*)(khb + (long)(((KT) << 7) + r) * 64 + c * 8);   \
      *(uint4*)((char*)Ks[BUF] + r * 128 + ((c * 16) ^ ((r & 7) << 4))) = d; } \
    { int r = u >> 4, c = u & 15;                                              \
      uint4 d = *(const uint4*)(vtb + (long)r * 2048 + ((KT) << 7) + c * 8);   \
      *(uint4*)((char*)Vs[BUF] + r * 256 + ((c * 16) ^ ((r & 7) << 4))) = d; } \
  }

#define STAGE_K(KT, BUF)                                                       \
  _Pragma("unroll") for (int i = 0; i < 4; ++i) {                              \
    int u = tid + (i << 8), r = u >> 3, c = u & 7;                             \
    uint4 d = *(const uint4*)(khb + (long)(((KT) << 7) + r) * 64 + c * 8);     \
    *(uint4*)((char*)Ks[BUF] + r * 128 + ((c * 16) ^ ((r & 7) << 4))) = d;     \
  }

  // ---------------- PASS 1: exp-sum + unnormalized PV ----------------
  STAGE_KV(0, 0);
  __syncthreads();
  for (int kt = 0; kt < 16; ++kt) {
    const int cur = kt & 1;
    if (kt < 15) STAGE_KV(kt + 1, cur ^ 1);   // overlaps with compute below
    const unsigned short* Kc = Ks[cur];
    const unsigned short* Vc = Vs[cur];
    f32x4 fa[8];
    __builtin_amdgcn_s_setprio(1);
#pragma unroll
    for (int nt = 0; nt < 8; ++nt) {
      int rk = (nt << 4) + lo;
      int swk = (rk & 7) << 4;
      f16x8 k0 = *(const f16x8*)((const char*)Kc + rk * 128 + (cb0 ^ swk));
      f16x8 k1 = *(const f16x8*)((const char*)Kc + rk * 128 + ((64 + cb0) ^ swk));
      f32x4 z = {};
      z = MFMA16(k0, aq0, z);
      z = MFMA16(k1, aq1, z);
      fa[nt] = z;
    }
    __builtin_amdgcn_s_setprio(0);
    ull mw0 = mrow[(kt << 1)], mw1 = mrow[(kt << 1) + 1];
    const bool fast = __all((int)((mw0 & mw1) == ~0ull));
#pragma unroll
    for (int nt = 0; nt < 8; ++nt) {
      float e0 = __builtin_amdgcn_exp2f(fa[nt][0] * cs);
      float e1 = __builtin_amdgcn_exp2f(fa[nt][1] * cs);
      float e2 = __builtin_amdgcn_exp2f(fa[nt][2] * cs);
      float e3 = __builtin_amdgcn_exp2f(fa[nt][3] * cs);
      if (!fast) {
        int kb = (nt << 4) + (hi << 2);
        ull mws = (kb & 64) ? mw1 : mw0;
        int sh = kb & 63;
        if (!((mws >> sh) & 1ull)) e0 = 0.f;
        if (!((mws >> (sh + 1)) & 1ull)) e1 = 0.f;
        if (!((mws >> (sh + 2)) & 1ull)) e2 = 0.f;
        if (!((mws >> (sh + 3)) & 1ull)) e3 = 0.f;
      }
      ll += (e0 + e1) + (e2 + e3);
      ull pk = (ull)pk2_(e0, e1) | ((ull)pk2_(e2, e3) << 32);
      *(ull*)((char*)Ps + rq * 256 + (((nt << 5) + (hi << 3)) ^ swq)) = pk;
    }
    f16x8 ap[4];
#pragma unroll
    for (int ks = 0; ks < 4; ++ks)
      ap[ks] = *(const f16x8*)((char*)Ps + rq * 256 + (((ks << 6) + cb0) ^ swq));
    __builtin_amdgcn_s_setprio(1);
#pragma unroll
    for (int nt = 0; nt < 4; ++nt) {
      int rv = (nt << 4) + lo;
      int swv = (rv & 7) << 4;
#pragma unroll
      for (int ks = 0; ks < 4; ++ks) {
        f16x8 bvv = *(const f16x8*)((const char*)Vc + rv * 256 + (((ks << 6) + cb0) ^ swv));
        oacc[nt] = MFMA16(ap[ks], bvv, oacc[nt]);
      }
    }
    __builtin_amdgcn_s_setprio(0);
    __syncthreads();
  }
  ll += __shfl_xor(ll, 16);
  ll += __shfl_xor(ll, 32);
  const float rl = (ll > 0.f) ? (1.f / ll) : 0.f;
  const float lrl = __log2f(rl);   // -inf when rl==0 -> exp2 -> 0

  // epilogue: O (normalized) -> oh f16 [4096][1024]
  float rlr[4];
#pragma unroll
  for (int r = 0; r < 4; ++r) rlr[r] = __shfl(rl, (hi << 2) + r, 16);
#pragma unroll
  for (int nt = 0; nt < 4; ++nt)
#pragma unroll
    for (int r = 0; r < 4; ++r) {
      int qe = q0 + (wave << 4) + (hi << 2) + r;
      oh[(long)(b_ * 2048 + qe) * 1024 + ((bh & 15) << 6) + (nt << 4) + lo] =
          f2h_(oacc[nt][r] * rlr[r]);
    }

  // ---------------- PASS 2: recompute + stream attn ----------------
  float* arow = attnp + ((long)bh * 2048 + qg) * 2048;
  STAGE_K(0, 0);
  __syncthreads();
  for (int kt = 0; kt < 16; ++kt) {
    const int cur = kt & 1;
    if (kt < 15) STAGE_K(kt + 1, cur ^ 1);
    const unsigned short* Kc = Ks[cur];
    f32x4 fa[8];
    __builtin_amdgcn_s_setprio(1);
#pragma unroll
    for (int nt = 0; nt < 8; ++nt) {
      int rk = (nt << 4) + lo;
      int swk = (rk & 7) << 4;
      f16x8 k0 = *(const f16x8*)((const char*)Kc + rk * 128 + (cb0 ^ swk));
      f16x8 k1 = *(const f16x8*)((const char*)Kc + rk * 128 + ((64 + cb0) ^ swk));
      f32x4 z = {};
      z = MFMA16(k0, aq0, z);
      z = MFMA16(k1, aq1, z);
      fa[nt] = z;
    }
    __builtin_amdgcn_s_setprio(0);
    ull mw0 = mrow[(kt << 1)], mw1 = mrow[(kt << 1) + 1];
    const bool fast = __all((int)((mw0 & mw1) == ~0ull));
#pragma unroll
    for (int nt = 0; nt < 8; ++nt) {
      float e0 = __builtin_amdgcn_exp2f(fa[nt][0] * cs + lrl);
      float e1 = __builtin_amdgcn_exp2f(fa[nt][1] * cs + lrl);
      float e2 = __builtin_amdgcn_exp2f(fa[nt][2] * cs + lrl);
      float e3 = __builtin_amdgcn_exp2f(fa[nt][3] * cs + lrl);
      if (!fast) {
        int kb = (nt << 4) + (hi << 2);
        ull mws = (kb & 64) ? mw1 : mw0;
        int sh = kb & 63;
        if (!((mws >> sh) & 1ull)) e0 = 0.f;
        if (!((mws >> (sh + 1)) & 1ull)) e1 = 0.f;
        if (!((mws >> (sh + 2)) & 1ull)) e2 = 0.f;
        if (!((mws >> (sh + 3)) & 1ull)) e3 = 0.f;
      }
      f32x4 st; st[0] = e0; st[1] = e1; st[2] = e2; st[3] = e3;
      __builtin_nontemporal_store(st, (f32x4*)(arow + (kt << 7) + (nt << 4) + (hi << 2)));
    }
    __syncthreads();
  }
}

// ---------------------------------------------------------------------------
extern "C" void kernel_launch(void* const* d_in, const int* in_sizes, int n_in,
                              void* d_out, int out_size, void* d_ws, size_t ws_size,
                              hipStream_t stream) {
  const float* q = (const float*)d_in[0];
  const float* k = (const float*)d_in[1];
  const float* v = (const float*)d_in[2];
  const int* mask = (const int*)d_in[3];
  const float* Wq = (const float*)d_in[4];
  const float* bq = (const float*)d_in[5];
  const float* Wk = (const float*)d_in[6];
  const float* bk = (const float*)d_in[7];
  const float* Wv = (const float*)d_in[8];
  const float* bv = (const float*)d_in[9];
  const float* Wf = (const float*)d_in[10];
  const float* bf_ = (const float*)d_in[11];

  float* out = (float*)d_out;
  float* attn = out + 4194304;

  unsigned short* xb = (unsigned short*)d_ws;
  unsigned short* qhp = xb + 16777216;
  unsigned short* khp = qhp + 4194304;
  unsigned short* vtp = khp + 4194304;
  unsigned short* ohp = vtp + 4194304;
  ull* mb = (ull*)((char*)d_ws + 67108864);

  prep_kernel<<<dim3(8704), dim3(256), 0, stream>>>(q, k, v, Wq, Wk, Wv, Wf, xb,
                                                    mask, mb);
  gemm_qkv<<<dim3(32, 8, 3), dim3(256), 0, stream>>>(xb, bq, bk, bv, qhp);
  attn_kernel<<<dim3(1024), dim3(256), 0, stream>>>(qhp, khp, vtp, mb, attn, ohp);
  gemm_f<<<dim3(32, 8), dim3(256), 0, stream>>>(xb, ohp, bf_, out);
}

// Round 13
// 307.255 us; speedup vs baseline: 1.0975x; 1.0975x over previous
//
#include <hip/hip_runtime.h>
#include <stdint.h>

// B=2, S=2048, DM=1024, H=16, HD=64
// out_size = 4194304 (out f32) + 134217728 (attn f32)

typedef _Float16 f16x8 __attribute__((ext_vector_type(8)));
typedef __fp16 fp16v2 __attribute__((ext_vector_type(2)));
typedef float f32x4 __attribute__((ext_vector_type(4)));
typedef unsigned long long ull;

static_assert(sizeof(f16x8) == 16, "f16x8 must be 16B");

#define MFMA16(a, b, c) __builtin_amdgcn_mfma_f32_16x16x32_f16((a), (b), (c), 0, 0, 0)

__device__ __forceinline__ unsigned short f2h_(float f) {
  _Float16 h = (_Float16)f;
  return __builtin_bit_cast(unsigned short, h);
}

// pack two f32 -> two f16 in one v_cvt_pkrtz_f16_f32
__device__ __forceinline__ unsigned pk2_(float a, float b) {
  fp16v2 h = __builtin_amdgcn_cvt_pkrtz(a, b);
  return __builtin_bit_cast(unsigned, h);
}

// ---------------------------------------------------------------------------
// 1) fused prep: blocks 0..8191 convert fp32->fp16 (q,k,v,W*); blocks
//    8192..8703 pack mask int32 -> bitmask u64 [B*S][32].
//    Source reads nontemporal (read-once streams; keep L2 for xb).
// ---------------------------------------------------------------------------
__global__ __launch_bounds__(256) void prep_kernel(
    const float* __restrict__ q, const float* __restrict__ k,
    const float* __restrict__ v, const float* __restrict__ wq,
    const float* __restrict__ wk, const float* __restrict__ wv,
    const float* __restrict__ wf, unsigned short* __restrict__ dst,
    const int* __restrict__ mask, ull* __restrict__ mb) {
  int bid = blockIdx.x;
  if (bid < 8192) {
    long e0 = ((long)bid * 256 + threadIdx.x) * 8;
    const float* src; long off;
    if (e0 < 4194304L)       { src = q;  off = e0; }
    else if (e0 < 8388608L)  { src = k;  off = e0 - 4194304L; }
    else if (e0 < 12582912L) { src = v;  off = e0 - 8388608L; }
    else if (e0 < 13631488L) { src = wq; off = e0 - 12582912L; }
    else if (e0 < 14680064L) { src = wk; off = e0 - 13631488L; }
    else if (e0 < 15728640L) { src = wv; off = e0 - 14680064L; }
    else                     { src = wf; off = e0 - 15728640L; }
    f32x4 a = __builtin_nontemporal_load((const f32x4*)(src + off));
    f32x4 b = __builtin_nontemporal_load((const f32x4*)(src + off + 4));
    uint4 o;
    o.x = pk2_(a[0], a[1]);
    o.y = pk2_(a[2], a[3]);
    o.z = pk2_(b[0], b[1]);
    o.w = pk2_(b[2], b[3]);
    *(uint4*)(dst + e0) = o;
  } else {
    int wid = (int)(((bid - 8192) * 256 + threadIdx.x) >> 6);
    int lane = threadIdx.x & 63;
    for (int w = wid; w < 131072; w += 2048) {
      int val = __builtin_nontemporal_load(mask + (long)w * 64 + lane);
      ull bits = __ballot(val != 0);
      if (lane == 0) mb[w] = bits;
    }
  }
}

// ---------------------------------------------------------------------------
// 3) GEMM: C[i][j] = sum_k A[i][k]*B[j][k] + bias[i]; 128x128 tile, 4 waves,
//    BK=64, reg-staged swizzled LDS, 4x4 acc per wave. Ping-pong double-
//    buffer: stage kt+1 before compute kt, ONE barrier/kt.
// ---------------------------------------------------------------------------
__device__ __forceinline__ void gemm_body(
    const unsigned short* __restrict__ A, const unsigned short* __restrict__ Bm,
    const float* __restrict__ bias, unsigned short* __restrict__ outb,
    float* __restrict__ outf, int mode) {
  __shared__ unsigned short Al[2][128 * 64];
  __shared__ unsigned short Bl[2][128 * 64];
  const int tid = threadIdx.x, lane = tid & 63, wave = tid >> 6;
  const int lo = lane & 15, hi = lane >> 4;
  const int wi = wave >> 1, wj = wave & 1;
  const int ib = blockIdx.y << 7, jb = blockIdx.x << 7;
  const int cb0 = hi << 4;
  f32x4 acc[4][4] = {};

#define GSTAGE(KT, BUF)                                                         \
  _Pragma("unroll") for (int i = 0; i < 4; ++i) {                               \
    int u = tid + (i << 8), r = u >> 3, c = u & 7;                              \
    uint4 av = *(const uint4*)(A + (long)(ib + r) * 1024 + ((KT) << 6) + c * 8);\
    uint4 bv = *(const uint4*)(Bm + (long)(jb + r) * 1024 + ((KT) << 6) + c * 8);\
    *(uint4*)((char*)Al[BUF] + r * 128 + ((c * 16) ^ ((r & 7) << 4))) = av;     \
    *(uint4*)((char*)Bl[BUF] + r * 128 + ((c * 16) ^ ((r & 7) << 4))) = bv;     \
  }

  GSTAGE(0, 0);
  __syncthreads();
  for (int kt = 0; kt < 16; ++kt) {
    const int cur = kt & 1;
    if (kt < 15) GSTAGE(kt + 1, cur ^ 1);
    f16x8 af[4][2], bfr[4][2];
#pragma unroll
    for (int it = 0; it < 4; ++it) {
      int r = (wi << 6) + (it << 4) + lo;
      af[it][0] = *(const f16x8*)((char*)Al[cur] + r * 128 + (cb0 ^ ((r & 7) << 4)));
      af[it][1] = *(const f16x8*)((char*)Al[cur] + r * 128 + ((64 + cb0) ^ ((r & 7) << 4)));
    }
#pragma unroll
    for (int jt = 0; jt < 4; ++jt) {
      int r = (wj << 6) + (jt << 4) + lo;
      bfr[jt][0] = *(const f16x8*)((char*)Bl[cur] + r * 128 + (cb0 ^ ((r & 7) << 4)));
      bfr[jt][1] = *(const f16x8*)((char*)Bl[cur] + r * 128 + ((64 + cb0) ^ ((r & 7) << 4)));
    }
#pragma unroll
    for (int it = 0; it < 4; ++it)
#pragma unroll
      for (int jt = 0; jt < 4; ++jt) {
        acc[it][jt] = MFMA16(af[it][0], bfr[jt][0], acc[it][jt]);
        acc[it][jt] = MFMA16(af[it][1], bfr[jt][1], acc[it][jt]);
      }
    __syncthreads();
  }
#pragma unroll
  for (int it = 0; it < 4; ++it)
#pragma unroll
    for (int jt = 0; jt < 4; ++jt) {
      f32x4 vv = acc[it][jt];
      int i0 = ib + (wi << 6) + (it << 4) + (hi << 2);
      int j = jb + (wj << 6) + (jt << 4) + lo;
      float4 bb = *(const float4*)(bias + i0);
      vv[0] += bb.x; vv[1] += bb.y; vv[2] += bb.z; vv[3] += bb.w;
      if (mode == 2) {
        float4 st; st.x = vv[0]; st.y = vv[1]; st.z = vv[2]; st.w = vv[3];
        *(float4*)(outf + (long)j * 1024 + i0) = st;
      } else {
        int h = i0 >> 6, dd = i0 & 63, b2 = j >> 11, s2 = j & 2047;
        if (mode == 0) {
          ull pk = (ull)f2h_(vv[0]) | ((ull)f2h_(vv[1]) << 16) |
                   ((ull)f2h_(vv[2]) << 32) | ((ull)f2h_(vv[3]) << 48);
          *(ull*)(outb + ((long)((b2 * 16 + h) * 2048 + s2)) * 64 + dd) = pk;
        } else {
          unsigned short* p = outb + ((long)((b2 * 16 + h) * 64 + dd)) * 2048 + s2;
          p[0] = f2h_(vv[0]); p[2048] = f2h_(vv[1]);
          p[4096] = f2h_(vv[2]); p[6144] = f2h_(vv[3]);
        }
      }
    }
}

__global__ __launch_bounds__(256) void gemm_qkv(
    const unsigned short* __restrict__ xb, const float* __restrict__ bq,
    const float* __restrict__ bk, const float* __restrict__ bv,
    unsigned short* __restrict__ outbase) {
  const int z = blockIdx.z;
  const unsigned short* A = xb + 12582912 + (long)z * 1048576;
  const unsigned short* Bm = xb + (long)z * 4194304;
  const float* bias = (z == 0) ? bq : ((z == 1) ? bk : bv);
  unsigned short* outp = outbase + (long)z * 4194304;
  gemm_body(A, Bm, bias, outp, nullptr, (z == 2) ? 1 : 0);
}

__global__ __launch_bounds__(256) void gemm_f(
    const unsigned short* __restrict__ xb, const unsigned short* __restrict__ oh,
    const float* __restrict__ bias, float* __restrict__ outf) {
  gemm_body(xb + 15728640, oh, bias, nullptr, outf, 2);
}

// ---------------------------------------------------------------------------
// 4) attention monolith, ping-pong double-buffer (R10/R11 champion, NO setprio).
// ---------------------------------------------------------------------------
__global__ __launch_bounds__(256, 2) void attn_kernel(
    const unsigned short* __restrict__ qh, const unsigned short* __restrict__ kh,
    const unsigned short* __restrict__ vt, const ull* __restrict__ mb,
    float* __restrict__ attnp, unsigned short* __restrict__ oh) {
  __shared__ unsigned short Ks[2][128 * 64];   // [k][d] swizzled, db (32 KB)
  __shared__ unsigned short Vs[2][64 * 128];   // [d][s] swizzled, db (32 KB)
  __shared__ unsigned short Ps[64 * 128];      // [q][k] swizzled, per-wave rows
  const int tid = threadIdx.x, lane = tid & 63, wave = tid >> 6;
  const int lo = lane & 15, hi = lane >> 4;
  const int cb0 = hi << 4;
  int id = blockIdx.x;
  int wgid = (id & 7) * 128 + (id >> 3);   // bijective XCD swizzle (nwg=1024)
  const int bh = wgid >> 5, b_ = bh >> 4;
  const int q0 = (wgid & 31) << 6;
  const float cs = 0.18033688011112042f;   // (1/8) * log2(e)

  const int rq = (wave << 4) + lo;   // local q row (0..63)
  const int qg = q0 + rq;            // global q
  const int swq = (rq & 7) << 4;
  const unsigned short* qp = qh + ((long)bh * 2048 + qg) * 64;
  f16x8 aq0 = *(const f16x8*)(qp + (hi << 3));
  f16x8 aq1 = *(const f16x8*)(qp + 32 + (hi << 3));
  const ull* mrow = mb + (long)(b_ * 2048 + qg) * 32;
  const unsigned short* khb = kh + (long)bh * 2048 * 64;
  const unsigned short* vtb = vt + (long)bh * 64 * 2048;

  float ll = 0.f;
  f32x4 oacc[4] = {};

#define STAGE_KV(KT, BUF)                                                      \
  _Pragma("unroll") for (int i = 0; i < 4; ++i) {                              \
    int u = tid + (i << 8);                                                    \
    { int r = u >> 3, c = u & 7;                                               \
      uint4 d = *(const uint4*)(khb + (long)(((KT) << 7) + r) * 64 + c * 8);   \
      *(uint4*)((char*)Ks[BUF] + r * 128 + ((c * 16) ^ ((r & 7) << 4))) = d; } \
    { int r = u >> 4, c = u & 15;                                              \
      uint4 d = *(const uint4*)(vtb + (long)r * 2048 + ((KT) << 7) + c * 8);   \
      *(uint4*)((char*)Vs[BUF] + r * 256 + ((c * 16) ^ ((r & 7) << 4))) = d; } \
  }

#define STAGE_K(KT, BUF)                                                       \
  _Pragma("unroll") for (int i = 0; i < 4; ++i) {                              \
    int u = tid + (i << 8), r = u >> 3, c = u & 7;                             \
    uint4 d = *(const uint4*)(khb + (long)(((KT) << 7) + r) * 64 + c * 8);     \
    *(uint4*)((char*)Ks[BUF] + r * 128 + ((c * 16) ^ ((r & 7) << 4))) = d;     \
  }

  // ---------------- PASS 1: exp-sum + unnormalized PV ----------------
  STAGE_KV(0, 0);
  __syncthreads();
  for (int kt = 0; kt < 16; ++kt) {
    const int cur = kt & 1;
    if (kt < 15) STAGE_KV(kt + 1, cur ^ 1);   // overlaps with compute below
    const unsigned short* Kc = Ks[cur];
    const unsigned short* Vc = Vs[cur];
    f32x4 fa[8];
#pragma unroll
    for (int nt = 0; nt < 8; ++nt) {
      int rk = (nt << 4) + lo;
      int swk = (rk & 7) << 4;
      f16x8 k0 = *(const f16x8*)((const char*)Kc + rk * 128 + (cb0 ^ swk));
      f16x8 k1 = *(const f16x8*)((const char*)Kc + rk * 128 + ((64 + cb0) ^ swk));
      f32x4 z = {};
      z = MFMA16(k0, aq0, z);
      z = MFMA16(k1, aq1, z);
      fa[nt] = z;
    }
    ull mw0 = mrow[(kt << 1)], mw1 = mrow[(kt << 1) + 1];
    const bool fast = __all((int)((mw0 & mw1) == ~0ull));
#pragma unroll
    for (int nt = 0; nt < 8; ++nt) {
      float e0 = __builtin_amdgcn_exp2f(fa[nt][0] * cs);
      float e1 = __builtin_amdgcn_exp2f(fa[nt][1] * cs);
      float e2 = __builtin_amdgcn_exp2f(fa[nt][2] * cs);
      float e3 = __builtin_amdgcn_exp2f(fa[nt][3] * cs);
      if (!fast) {
        int kb = (nt << 4) + (hi << 2);
        ull mws = (kb & 64) ? mw1 : mw0;
        int sh = kb & 63;
        if (!((mws >> sh) & 1ull)) e0 = 0.f;
        if (!((mws >> (sh + 1)) & 1ull)) e1 = 0.f;
        if (!((mws >> (sh + 2)) & 1ull)) e2 = 0.f;
        if (!((mws >> (sh + 3)) & 1ull)) e3 = 0.f;
      }
      ll += (e0 + e1) + (e2 + e3);
      ull pk = (ull)pk2_(e0, e1) | ((ull)pk2_(e2, e3) << 32);
      *(ull*)((char*)Ps + rq * 256 + (((nt << 5) + (hi << 3)) ^ swq)) = pk;
    }
    f16x8 ap[4];
#pragma unroll
    for (int ks = 0; ks < 4; ++ks)
      ap[ks] = *(const f16x8*)((char*)Ps + rq * 256 + (((ks << 6) + cb0) ^ swq));
#pragma unroll
    for (int nt = 0; nt < 4; ++nt) {
      int rv = (nt << 4) + lo;
      int swv = (rv & 7) << 4;
#pragma unroll
      for (int ks = 0; ks < 4; ++ks) {
        f16x8 bvv = *(const f16x8*)((const char*)Vc + rv * 256 + (((ks << 6) + cb0) ^ swv));
        oacc[nt] = MFMA16(ap[ks], bvv, oacc[nt]);
      }
    }
    __syncthreads();
  }
  ll += __shfl_xor(ll, 16);
  ll += __shfl_xor(ll, 32);
  const float rl = (ll > 0.f) ? (1.f / ll) : 0.f;
  const float lrl = __log2f(rl);   // -inf when rl==0 -> exp2 -> 0

  // epilogue: O (normalized) -> oh f16 [4096][1024]
  float rlr[4];
#pragma unroll
  for (int r = 0; r < 4; ++r) rlr[r] = __shfl(rl, (hi << 2) + r, 16);
#pragma unroll
  for (int nt = 0; nt < 4; ++nt)
#pragma unroll
    for (int r = 0; r < 4; ++r) {
      int qe = q0 + (wave << 4) + (hi << 2) + r;
      oh[(long)(b_ * 2048 + qe) * 1024 + ((bh & 15) << 6) + (nt << 4) + lo] =
          f2h_(oacc[nt][r] * rlr[r]);
    }

  // ---------------- PASS 2: recompute + stream attn ----------------
  float* arow = attnp + ((long)bh * 2048 + qg) * 2048;
  STAGE_K(0, 0);
  __syncthreads();
  for (int kt = 0; kt < 16; ++kt) {
    const int cur = kt & 1;
    if (kt < 15) STAGE_K(kt + 1, cur ^ 1);
    const unsigned short* Kc = Ks[cur];
    f32x4 fa[8];
#pragma unroll
    for (int nt = 0; nt < 8; ++nt) {
      int rk = (nt << 4) + lo;
      int swk = (rk & 7) << 4;
      f16x8 k0 = *(const f16x8*)((const char*)Kc + rk * 128 + (cb0 ^ swk));
      f16x8 k1 = *(const f16x8*)((const char*)Kc + rk * 128 + ((64 + cb0) ^ swk));
      f32x4 z = {};
      z = MFMA16(k0, aq0, z);
      z = MFMA16(k1, aq1, z);
      fa[nt] = z;
    }
    ull mw0 = mrow[(kt << 1)], mw1 = mrow[(kt << 1) + 1];
    const bool fast = __all((int)((mw0 & mw1) == ~0ull));
#pragma unroll
    for (int nt = 0; nt < 8; ++nt) {
      float e0 = __builtin_amdgcn_exp2f(fa[nt][0] * cs + lrl);
      float e1 = __builtin_amdgcn_exp2f(fa[nt][1] * cs + lrl);
      float e2 = __builtin_amdgcn_exp2f(fa[nt][2] * cs + lrl);
      float e3 = __builtin_amdgcn_exp2f(fa[nt][3] * cs + lrl);
      if (!fast) {
        int kb = (nt << 4) + (hi << 2);
        ull mws = (kb & 64) ? mw1 : mw0;
        int sh = kb & 63;
        if (!((mws >> sh) & 1ull)) e0 = 0.f;
        if (!((mws >> (sh + 1)) & 1ull)) e1 = 0.f;
        if (!((mws >> (sh + 2)) & 1ull)) e2 = 0.f;
        if (!((mws >> (sh + 3)) & 1ull)) e3 = 0.f;
      }
      f32x4 st; st[0] = e0; st[1] = e1; st[2] = e2; st[3] = e3;
      __builtin_nontemporal_store(st, (f32x4*)(arow + (kt << 7) + (nt << 4) + (hi << 2)));
    }
    __syncthreads();
  }
}

// ---------------------------------------------------------------------------
extern "C" void kernel_launch(void* const* d_in, const int* in_sizes, int n_in,
                              void* d_out, int out_size, void* d_ws, size_t ws_size,
                              hipStream_t stream) {
  const float* q = (const float*)d_in[0];
  const float* k = (const float*)d_in[1];
  const float* v = (const float*)d_in[2];
  const int* mask = (const int*)d_in[3];
  const float* Wq = (const float*)d_in[4];
  const float* bq = (const float*)d_in[5];
  const float* Wk = (const float*)d_in[6];
  const float* bk = (const float*)d_in[7];
  const float* Wv = (const float*)d_in[8];
  const float* bv = (const float*)d_in[9];
  const float* Wf = (const float*)d_in[10];
  const float* bf_ = (const float*)d_in[11];

  float* out = (float*)d_out;
  float* attn = out + 4194304;

  unsigned short* xb = (unsigned short*)d_ws;
  unsigned short* qhp = xb + 16777216;
  unsigned short* khp = qhp + 4194304;
  unsigned short* vtp = khp + 4194304;
  unsigned short* ohp = vtp + 4194304;
  ull* mb = (ull*)((char*)d_ws + 67108864);

  prep_kernel<<<dim3(8704), dim3(256), 0, stream>>>(q, k, v, Wq, Wk, Wv, Wf, xb,
                                                    mask, mb);
  gemm_qkv<<<dim3(32, 8, 3), dim3(256), 0, stream>>>(xb, bq, bk, bv, qhp);
  attn_kernel<<<dim3(1024), dim3(256), 0, stream>>>(qhp, khp, vtp, mb, attn, ohp);
  gemm_f<<<dim3(32, 8), dim3(256), 0, stream>>>(xb, ohp, bf_, out);
}

// Round 14
// 292.553 us; speedup vs baseline: 1.1527x; 1.0503x over previous
//
#include <hip/hip_runtime.h>
#include <stdint.h>

// B=2, S=2048, DM=1024, H=16, HD=64
// out_size = 4194304 (out f32) + 134217728 (attn f32)

typedef _Float16 f16x8 __attribute__((ext_vector_type(8)));
typedef __fp16 fp16v2 __attribute__((ext_vector_type(2)));
typedef float f32x4 __attribute__((ext_vector_type(4)));
typedef unsigned long long ull;

static_assert(sizeof(f16x8) == 16, "f16x8 must be 16B");

#define MFMA16(a, b, c) __builtin_amdgcn_mfma_f32_16x16x32_f16((a), (b), (c), 0, 0, 0)

__device__ __forceinline__ unsigned short f2h_(float f) {
  _Float16 h = (_Float16)f;
  return __builtin_bit_cast(unsigned short, h);
}

// pack two f32 -> two f16 in one v_cvt_pkrtz_f16_f32
__device__ __forceinline__ unsigned pk2_(float a, float b) {
  fp16v2 h = __builtin_amdgcn_cvt_pkrtz(a, b);
  return __builtin_bit_cast(unsigned, h);
}

// ---------------------------------------------------------------------------
// 1) fused prep: blocks 0..8191 convert fp32->fp16 (q,k,v,W*); blocks
//    8192..8703 pack mask int32 -> bitmask u64 [B*S][32].
//    Regular loads (NT load hint measured -15us in R13).
// ---------------------------------------------------------------------------
__global__ __launch_bounds__(256) void prep_kernel(
    const float* __restrict__ q, const float* __restrict__ k,
    const float* __restrict__ v, const float* __restrict__ wq,
    const float* __restrict__ wk, const float* __restrict__ wv,
    const float* __restrict__ wf, unsigned short* __restrict__ dst,
    const int* __restrict__ mask, ull* __restrict__ mb) {
  int bid = blockIdx.x;
  if (bid < 8192) {
    long e0 = ((long)bid * 256 + threadIdx.x) * 8;
    const float* src; long off;
    if (e0 < 4194304L)       { src = q;  off = e0; }
    else if (e0 < 8388608L)  { src = k;  off = e0 - 4194304L; }
    else if (e0 < 12582912L) { src = v;  off = e0 - 8388608L; }
    else if (e0 < 13631488L) { src = wq; off = e0 - 12582912L; }
    else if (e0 < 14680064L) { src = wk; off = e0 - 13631488L; }
    else if (e0 < 15728640L) { src = wv; off = e0 - 14680064L; }
    else                     { src = wf; off = e0 - 15728640L; }
    float4 a = *(const float4*)(src + off);
    float4 b = *(const float4*)(src + off + 4);
    uint4 o;
    o.x = pk2_(a.x, a.y);
    o.y = pk2_(a.z, a.w);
    o.z = pk2_(b.x, b.y);
    o.w = pk2_(b.z, b.w);
    *(uint4*)(dst + e0) = o;
  } else {
    int wid = (int)(((bid - 8192) * 256 + threadIdx.x) >> 6);
    int lane = threadIdx.x & 63;
    for (int w = wid; w < 131072; w += 2048) {
      int val = mask[(long)w * 64 + lane];
      ull bits = __ballot(val != 0);
      if (lane == 0) mb[w] = bits;
    }
  }
}

// ---------------------------------------------------------------------------
// 3) GEMM: C[i][j] = sum_k A[i][k]*B[j][k] + bias[i]; 128x128 tile, 4 waves,
//    BK=64, reg-staged swizzled LDS, 4x4 acc per wave. Ping-pong double-
//    buffer: stage kt+1 before compute kt, ONE barrier/kt.
// ---------------------------------------------------------------------------
__device__ __forceinline__ void gemm_body(
    const unsigned short* __restrict__ A, const unsigned short* __restrict__ Bm,
    const float* __restrict__ bias, unsigned short* __restrict__ outb,
    float* __restrict__ outf, int mode) {
  __shared__ unsigned short Al[2][128 * 64];
  __shared__ unsigned short Bl[2][128 * 64];
  const int tid = threadIdx.x, lane = tid & 63, wave = tid >> 6;
  const int lo = lane & 15, hi = lane >> 4;
  const int wi = wave >> 1, wj = wave & 1;
  const int ib = blockIdx.y << 7, jb = blockIdx.x << 7;
  const int cb0 = hi << 4;
  f32x4 acc[4][4] = {};

#define GSTAGE(KT, BUF)                                                         \
  _Pragma("unroll") for (int i = 0; i < 4; ++i) {                               \
    int u = tid + (i << 8), r = u >> 3, c = u & 7;                              \
    uint4 av = *(const uint4*)(A + (long)(ib + r) * 1024 + ((KT) << 6) + c * 8);\
    uint4 bv = *(const uint4*)(Bm + (long)(jb + r) * 1024 + ((KT) << 6) + c * 8);\
    *(uint4*)((char*)Al[BUF] + r * 128 + ((c * 16) ^ ((r & 7) << 4))) = av;     \
    *(uint4*)((char*)Bl[BUF] + r * 128 + ((c * 16) ^ ((r & 7) << 4))) = bv;     \
  }

  GSTAGE(0, 0);
  __syncthreads();
  for (int kt = 0; kt < 16; ++kt) {
    const int cur = kt & 1;
    if (kt < 15) GSTAGE(kt + 1, cur ^ 1);
    f16x8 af[4][2], bfr[4][2];
#pragma unroll
    for (int it = 0; it < 4; ++it) {
      int r = (wi << 6) + (it << 4) + lo;
      af[it][0] = *(const f16x8*)((char*)Al[cur] + r * 128 + (cb0 ^ ((r & 7) << 4)));
      af[it][1] = *(const f16x8*)((char*)Al[cur] + r * 128 + ((64 + cb0) ^ ((r & 7) << 4)));
    }
#pragma unroll
    for (int jt = 0; jt < 4; ++jt) {
      int r = (wj << 6) + (jt << 4) + lo;
      bfr[jt][0] = *(const f16x8*)((char*)Bl[cur] + r * 128 + (cb0 ^ ((r & 7) << 4)));
      bfr[jt][1] = *(const f16x8*)((char*)Bl[cur] + r * 128 + ((64 + cb0) ^ ((r & 7) << 4)));
    }
#pragma unroll
    for (int it = 0; it < 4; ++it)
#pragma unroll
      for (int jt = 0; jt < 4; ++jt) {
        acc[it][jt] = MFMA16(af[it][0], bfr[jt][0], acc[it][jt]);
        acc[it][jt] = MFMA16(af[it][1], bfr[jt][1], acc[it][jt]);
      }
    __syncthreads();
  }
#pragma unroll
  for (int it = 0; it < 4; ++it)
#pragma unroll
    for (int jt = 0; jt < 4; ++jt) {
      f32x4 vv = acc[it][jt];
      int i0 = ib + (wi << 6) + (it << 4) + (hi << 2);
      int j = jb + (wj << 6) + (jt << 4) + lo;
      float4 bb = *(const float4*)(bias + i0);
      vv[0] += bb.x; vv[1] += bb.y; vv[2] += bb.z; vv[3] += bb.w;
      if (mode == 2) {
        float4 st; st.x = vv[0]; st.y = vv[1]; st.z = vv[2]; st.w = vv[3];
        *(float4*)(outf + (long)j * 1024 + i0) = st;
      } else {
        int h = i0 >> 6, dd = i0 & 63, b2 = j >> 11, s2 = j & 2047;
        if (mode == 0) {
          ull pk = (ull)f2h_(vv[0]) | ((ull)f2h_(vv[1]) << 16) |
                   ((ull)f2h_(vv[2]) << 32) | ((ull)f2h_(vv[3]) << 48);
          *(ull*)(outb + ((long)((b2 * 16 + h) * 2048 + s2)) * 64 + dd) = pk;
        } else {
          unsigned short* p = outb + ((long)((b2 * 16 + h) * 64 + dd)) * 2048 + s2;
          p[0] = f2h_(vv[0]); p[2048] = f2h_(vv[1]);
          p[4096] = f2h_(vv[2]); p[6144] = f2h_(vv[3]);
        }
      }
    }
}

__global__ __launch_bounds__(256) void gemm_qkv(
    const unsigned short* __restrict__ xb, const float* __restrict__ bq,
    const float* __restrict__ bk, const float* __restrict__ bv,
    unsigned short* __restrict__ outbase) {
  const int z = blockIdx.z;
  const unsigned short* A = xb + 12582912 + (long)z * 1048576;
  const unsigned short* Bm = xb + (long)z * 4194304;
  const float* bias = (z == 0) ? bq : ((z == 1) ? bk : bv);
  unsigned short* outp = outbase + (long)z * 4194304;
  gemm_body(A, Bm, bias, outp, nullptr, (z == 2) ? 1 : 0);
}

__global__ __launch_bounds__(256) void gemm_f(
    const unsigned short* __restrict__ xb, const unsigned short* __restrict__ oh,
    const float* __restrict__ bias, float* __restrict__ outf) {
  gemm_body(xb + 15728640, oh, bias, nullptr, outf, 2);
}

// ---------------------------------------------------------------------------
// 4) attention monolith, ping-pong double-buffer (R10/R11 champion).
// ---------------------------------------------------------------------------
__global__ __launch_bounds__(256, 2) void attn_kernel(
    const unsigned short* __restrict__ qh, const unsigned short* __restrict__ kh,
    const unsigned short* __restrict__ vt, const ull* __restrict__ mb,
    float* __restrict__ attnp, unsigned short* __restrict__ oh) {
  __shared__ unsigned short Ks[2][128 * 64];   // [k][d] swizzled, db (32 KB)
  __shared__ unsigned short Vs[2][64 * 128];   // [d][s] swizzled, db (32 KB)
  __shared__ unsigned short Ps[64 * 128];      // [q][k] swizzled, per-wave rows
  const int tid = threadIdx.x, lane = tid & 63, wave = tid >> 6;
  const int lo = lane & 15, hi = lane >> 4;
  const int cb0 = hi << 4;
  int id = blockIdx.x;
  int wgid = (id & 7) * 128 + (id >> 3);   // bijective XCD swizzle (nwg=1024)
  const int bh = wgid >> 5, b_ = bh >> 4;
  const int q0 = (wgid & 31) << 6;
  const float cs = 0.18033688011112042f;   // (1/8) * log2(e)

  const int rq = (wave << 4) + lo;   // local q row (0..63)
  const int qg = q0 + rq;            // global q
  const int swq = (rq & 7) << 4;
  const unsigned short* qp = qh + ((long)bh * 2048 + qg) * 64;
  f16x8 aq0 = *(const f16x8*)(qp + (hi << 3));
  f16x8 aq1 = *(const f16x8*)(qp + 32 + (hi << 3));
  const ull* mrow = mb + (long)(b_ * 2048 + qg) * 32;
  const unsigned short* khb = kh + (long)bh * 2048 * 64;
  const unsigned short* vtb = vt + (long)bh * 64 * 2048;

  float ll = 0.f;
  f32x4 oacc[4] = {};

#define STAGE_KV(KT, BUF)                                                      \
  _Pragma("unroll") for (int i = 0; i < 4; ++i) {                              \
    int u = tid + (i << 8);                                                    \
    { int r = u >> 3, c = u & 7;                                               \
      uint4 d = *(const uint4*)(khb + (long)(((KT) << 7) + r) * 64 + c * 8);   \
      *(uint4*)((char*)Ks[BUF] + r * 128 + ((c * 16) ^ ((r & 7) << 4))) = d; } \
    { int r = u >> 4, c = u & 15;                                              \
      uint4 d = *(const uint4*)(vtb + (long)r * 2048 + ((KT) << 7) + c * 8);   \
      *(uint4*)((char*)Vs[BUF] + r * 256 + ((c * 16) ^ ((r & 7) << 4))) = d; } \
  }

#define STAGE_K(KT, BUF)                                                       \
  _Pragma("unroll") for (int i = 0; i < 4; ++i) {                              \
    int u = tid + (i << 8), r = u >> 3, c = u & 7;                             \
    uint4 d = *(const uint4*)(khb + (long)(((KT) << 7) + r) * 64 + c * 8);     \
    *(uint4*)((char*)Ks[BUF] + r * 128 + ((c * 16) ^ ((r & 7) << 4))) = d;     \
  }

  // ---------------- PASS 1: exp-sum + unnormalized PV ----------------
  STAGE_KV(0, 0);
  __syncthreads();
  for (int kt = 0; kt < 16; ++kt) {
    const int cur = kt & 1;
    if (kt < 15) STAGE_KV(kt + 1, cur ^ 1);   // overlaps with compute below
    const unsigned short* Kc = Ks[cur];
    const unsigned short* Vc = Vs[cur];
    f32x4 fa[8];
#pragma unroll
    for (int nt = 0; nt < 8; ++nt) {
      int rk = (nt << 4) + lo;
      int swk = (rk & 7) << 4;
      f16x8 k0 = *(const f16x8*)((const char*)Kc + rk * 128 + (cb0 ^ swk));
      f16x8 k1 = *(const f16x8*)((const char*)Kc + rk * 128 + ((64 + cb0) ^ swk));
      f32x4 z = {};
      z = MFMA16(k0, aq0, z);
      z = MFMA16(k1, aq1, z);
      fa[nt] = z;
    }
    ull mw0 = mrow[(kt << 1)], mw1 = mrow[(kt << 1) + 1];
    const bool fast = __all((int)((mw0 & mw1) == ~0ull));
#pragma unroll
    for (int nt = 0; nt < 8; ++nt) {
      float e0 = __builtin_amdgcn_exp2f(fa[nt][0] * cs);
      float e1 = __builtin_amdgcn_exp2f(fa[nt][1] * cs);
      float e2 = __builtin_amdgcn_exp2f(fa[nt][2] * cs);
      float e3 = __builtin_amdgcn_exp2f(fa[nt][3] * cs);
      if (!fast) {
        int kb = (nt << 4) + (hi << 2);
        ull mws = (kb & 64) ? mw1 : mw0;
        int sh = kb & 63;
        if (!((mws >> sh) & 1ull)) e0 = 0.f;
        if (!((mws >> (sh + 1)) & 1ull)) e1 = 0.f;
        if (!((mws >> (sh + 2)) & 1ull)) e2 = 0.f;
        if (!((mws >> (sh + 3)) & 1ull)) e3 = 0.f;
      }
      ll += (e0 + e1) + (e2 + e3);
      ull pk = (ull)pk2_(e0, e1) | ((ull)pk2_(e2, e3) << 32);
      *(ull*)((char*)Ps + rq * 256 + (((nt << 5) + (hi << 3)) ^ swq)) = pk;
    }
    f16x8 ap[4];
#pragma unroll
    for (int ks = 0; ks < 4; ++ks)
      ap[ks] = *(const f16x8*)((char*)Ps + rq * 256 + (((ks << 6) + cb0) ^ swq));
#pragma unroll
    for (int nt = 0; nt < 4; ++nt) {
      int rv = (nt << 4) + lo;
      int swv = (rv & 7) << 4;
#pragma unroll
      for (int ks = 0; ks < 4; ++ks) {
        f16x8 bvv = *(const f16x8*)((const char*)Vc + rv * 256 + (((ks << 6) + cb0) ^ swv));
        oacc[nt] = MFMA16(ap[ks], bvv, oacc[nt]);
      }
    }
    __syncthreads();
  }
  ll += __shfl_xor(ll, 16);
  ll += __shfl_xor(ll, 32);
  const float rl = (ll > 0.f) ? (1.f / ll) : 0.f;
  const float lrl = __log2f(rl);   // -inf when rl==0 -> exp2 -> 0

  // epilogue: O (normalized) -> oh f16 [4096][1024]
  float rlr[4];
#pragma unroll
  for (int r = 0; r < 4; ++r) rlr[r] = __shfl(rl, (hi << 2) + r, 16);
#pragma unroll
  for (int nt = 0; nt < 4; ++nt)
#pragma unroll
    for (int r = 0; r < 4; ++r) {
      int qe = q0 + (wave << 4) + (hi << 2) + r;
      oh[(long)(b_ * 2048 + qe) * 1024 + ((bh & 15) << 6) + (nt << 4) + lo] =
          f2h_(oacc[nt][r] * rlr[r]);
    }

  // ---------------- PASS 2: recompute + stream attn ----------------
  float* arow = attnp + ((long)bh * 2048 + qg) * 2048;
  STAGE_K(0, 0);
  __syncthreads();
  for (int kt = 0; kt < 16; ++kt) {
    const int cur = kt & 1;
    if (kt < 15) STAGE_K(kt + 1, cur ^ 1);
    const unsigned short* Kc = Ks[cur];
    f32x4 fa[8];
#pragma unroll
    for (int nt = 0; nt < 8; ++nt) {
      int rk = (nt << 4) + lo;
      int swk = (rk & 7) << 4;
      f16x8 k0 = *(const f16x8*)((const char*)Kc + rk * 128 + (cb0 ^ swk));
      f16x8 k1 = *(const f16x8*)((const char*)Kc + rk * 128 + ((64 + cb0) ^ swk));
      f32x4 z = {};
      z = MFMA16(k0, aq0, z);
      z = MFMA16(k1, aq1, z);
      fa[nt] = z;
    }
    ull mw0 = mrow[(kt << 1)], mw1 = mrow[(kt << 1) + 1];
    const bool fast = __all((int)((mw0 & mw1) == ~0ull));
#pragma unroll
    for (int nt = 0; nt < 8; ++nt) {
      float e0 = __builtin_amdgcn_exp2f(fa[nt][0] * cs + lrl);
      float e1 = __builtin_amdgcn_exp2f(fa[nt][1] * cs + lrl);
      float e2 = __builtin_amdgcn_exp2f(fa[nt][2] * cs + lrl);
      float e3 = __builtin_amdgcn_exp2f(fa[nt][3] * cs + lrl);
      if (!fast) {
        int kb = (nt << 4) + (hi << 2);
        ull mws = (kb & 64) ? mw1 : mw0;
        int sh = kb & 63;
        if (!((mws >> sh) & 1ull)) e0 = 0.f;
        if (!((mws >> (sh + 1)) & 1ull)) e1 = 0.f;
        if (!((mws >> (sh + 2)) & 1ull)) e2 = 0.f;
        if (!((mws >> (sh + 3)) & 1ull)) e3 = 0.f;
      }
      f32x4 st; st[0] = e0; st[1] = e1; st[2] = e2; st[3] = e3;
      __builtin_nontemporal_store(st, (f32x4*)(arow + (kt << 7) + (nt << 4) + (hi << 2)));
    }
    __syncthreads();
  }
}

// ---------------------------------------------------------------------------
extern "C" void kernel_launch(void* const* d_in, const int* in_sizes, int n_in,
                              void* d_out, int out_size, void* d_ws, size_t ws_size,
                              hipStream_t stream) {
  const float* q = (const float*)d_in[0];
  const float* k = (const float*)d_in[1];
  const float* v = (const float*)d_in[2];
  const int* mask = (const int*)d_in[3];
  const float* Wq = (const float*)d_in[4];
  const float* bq = (const float*)d_in[5];
  const float* Wk = (const float*)d_in[6];
  const float* bk = (const float*)d_in[7];
  const float* Wv = (const float*)d_in[8];
  const float* bv = (const float*)d_in[9];
  const float* Wf = (const float*)d_in[10];
  const float* bf_ = (const float*)d_in[11];

  float* out = (float*)d_out;
  float* attn = out + 4194304;

  unsigned short* xb = (unsigned short*)d_ws;
  unsigned short* qhp = xb + 16777216;
  unsigned short* khp = qhp + 4194304;
  unsigned short* vtp = khp + 4194304;
  unsigned short* ohp = vtp + 4194304;
  ull* mb = (ull*)((char*)d_ws + 67108864);

  prep_kernel<<<dim3(8704), dim3(256), 0, stream>>>(q, k, v, Wq, Wk, Wv, Wf, xb,
                                                    mask, mb);
  gemm_qkv<<<dim3(32, 8, 3), dim3(256), 0, stream>>>(xb, bq, bk, bv, qhp);
  attn_kernel<<<dim3(1024), dim3(256), 0, stream>>>(qhp, khp, vtp, mb, attn, ohp);
  gemm_f<<<dim3(32, 8), dim3(256), 0, stream>>>(xb, ohp, bf_, out);
}